// Round 1
// baseline (233.442 us; speedup 1.0000x reference)
//
#include <hip/hip_runtime.h>

#define BATCH 64
#define CH 31
#define HF 28
#define WF 28
#define NCELL 784   // 28*28
#define NCLS 21
#define BGCLS 20
#define SORTN 1024  // next pow2 >= NCELL

// ---------------------------------------------------------------------------
// Kernel 1: per-cell decode.
// features layout: [B][C][H][W] fp32 contiguous; cell n = h*WF + w.
// For fixed channel c, consecutive threads (consecutive n) read consecutive
// addresses -> coalesced.
// ---------------------------------------------------------------------------
__global__ void decode_kernel(const float* __restrict__ feat,
                              const int* __restrict__ hofp,
                              const int* __restrict__ wofp,
                              float* __restrict__ out,
                              float4* __restrict__ ws_box,
                              float* __restrict__ ws_score)
{
    int gid = blockIdx.x * blockDim.x + threadIdx.x;
    if (gid >= BATCH * NCELL) return;
    int b = gid / NCELL;
    int n = gid - b * NCELL;

    const float* base = feat + (size_t)b * CH * NCELL + n;
    float x[CH];
#pragma unroll
    for (int c = 0; c < CH; ++c) x[c] = base[(size_t)c * NCELL];

    // conf argmax over raw x[4], x[9] (first-occurrence on ties -> index 0)
    float c0 = x[4], c1 = x[9];
    int carg = (c1 > c0) ? 1 : 0;
    float cmax = fmaxf(c0, c1);

    // softmax over x[10..30]
    float m = x[10];
#pragma unroll
    for (int k = 1; k < NCLS; ++k) m = fmaxf(m, x[10 + k]);
    float e[NCLS];
    float sum = 0.0f;
#pragma unroll
    for (int k = 0; k < NCLS; ++k) { e[k] = expf(x[10 + k] - m); sum += e[k]; }

    // con_prob = cmax * softmax; argmax first-occurrence (strict >)
    float best = -INFINITY;
    int cat = 0;
#pragma unroll
    for (int k = 0; k < NCLS; ++k) {
        float cp = cmax * (e[k] / sum);
        if (cp > best) { best = cp; cat = k; }
    }

    // gather chosen bbox (constant indices + cndmask: stays in registers)
    float rx = carg ? x[5] : x[0];
    float ry = carg ? x[6] : x[1];
    float rw = carg ? x[7] : x[2];
    float rh = carg ? x[8] : x[3];
    rx = 1.0f / (1.0f + expf(-rx));
    ry = 1.0f / (1.0f + expf(-ry));
    rw = 1.0f / (1.0f + expf(-rw));
    rh = 1.0f / (1.0f + expf(-rh));

    float w_ori = (float)(*wofp), h_ori = (float)(*hofp);
    float sw = w_ori / (float)WF, sh = h_ori / (float)HF;
    float col = (float)(n % WF), row = (float)(n / WF);
    float cx = (rx + col) * sw;
    float cy = (ry + row) * sh;
    float bw = rw * w_ori;
    float bh = rh * h_ori;
    float x1 = cx - bw * 0.5f, y1 = cy - bh * 0.5f;
    float x2 = cx + bw * 0.5f, y2 = cy + bh * 0.5f;

    float* o = out + (size_t)gid * 7;
    o[0] = x1; o[1] = y1; o[2] = x2; o[3] = y2;
    o[4] = best; o[5] = (float)cat;
    // o[6] (keep flag) written by nms_kernel

    float off = (float)cat * 4096.0f;
    ws_box[gid] = make_float4(x1 + off, y1 + off, x2 + off, y2 + off);
    ws_score[gid] = (cat != BGCLS) ? best : -INFINITY;
}

// ---------------------------------------------------------------------------
// Kernel 2: per-batch stable descending sort (bitonic on 64-bit keys) +
// greedy NMS exactly matching the reference fori_loop, + keep-flag scatter.
// One block per batch, 1024 threads (16 waves).
// ---------------------------------------------------------------------------
__global__ __launch_bounds__(SORTN)
void nms_kernel(const float4* __restrict__ ws_box,
                const float* __restrict__ ws_score,
                float* __restrict__ out)
{
    int b = blockIdx.x;
    int t = threadIdx.x;

    __shared__ unsigned long long keys[SORTN];
    __shared__ float4 sbox[NCELL];
    __shared__ float  sarea[NCELL];
    __shared__ int    keep[NCELL];

    // Build key: high word = order-preserving uint of score, low word =
    // 0xFFFFFFFF - idx (descending sort => ties resolve to smaller idx first,
    // matching stable argsort(-s)).
    unsigned long long key = 0ull;   // pads sort last (all real keys > 0)
    if (t < NCELL) {
        float sc = ws_score[(size_t)b * NCELL + t];
        unsigned u = __float_as_uint(sc);
        u = (u & 0x80000000u) ? ~u : (u | 0x80000000u);
        key = ((unsigned long long)u << 32) |
              (unsigned long long)(0xFFFFFFFFu - (unsigned)t);
    }
    keys[t] = key;
    __syncthreads();

    // bitonic sort, descending
    for (int k = 2; k <= SORTN; k <<= 1) {
        for (int j = k >> 1; j > 0; j >>= 1) {
            int ixj = t ^ j;
            if (ixj > t) {
                unsigned long long a = keys[t], c2 = keys[ixj];
                bool descSeg = ((t & k) == 0);
                bool doswap = descSeg ? (a < c2) : (a > c2);
                if (doswap) { keys[t] = c2; keys[ixj] = a; }
            }
            __syncthreads();
        }
    }

    int orig = 0;
    float4 my = make_float4(0.f, 0.f, 0.f, 0.f);
    float myarea = 0.0f;
    if (t < NCELL) {
        unsigned long long kk = keys[t];
        orig = (int)(0xFFFFFFFFu - (unsigned)(kk & 0xFFFFFFFFull));
        float4 bb = ws_box[(size_t)b * NCELL + orig];
        sbox[t] = bb;
        float ar = fmaxf(bb.z - bb.x, 0.f) * fmaxf(bb.w - bb.y, 0.f);
        sarea[t] = ar;
        my = bb; myarea = ar;
        float sc = ws_score[(size_t)b * NCELL + orig];
        keep[t] = (sc != -INFINITY) ? 1 : 0;
    }
    __syncthreads();

    // greedy suppression: iteration i reads keep[i] (final by then); only
    // threads t > i may clear their own keep[t]. One barrier per iteration.
    for (int i = 0; i < NCELL - 1; ++i) {
        if (keep[i] && t > i && t < NCELL && keep[t]) {
            float4 bi = sbox[i];
            float xx1 = fmaxf(bi.x, my.x), yy1 = fmaxf(bi.y, my.y);
            float xx2 = fminf(bi.z, my.z), yy2 = fminf(bi.w, my.w);
            float inter = fmaxf(xx2 - xx1, 0.f) * fmaxf(yy2 - yy1, 0.f);
            float uni = sarea[i] + myarea - inter;
            float iou = inter / fmaxf(uni, 1e-9f);
            if (iou > 0.5f) keep[t] = 0;
        }
        __syncthreads();
    }

    if (t < NCELL) {
        out[((size_t)b * NCELL + orig) * 7 + 6] = keep[t] ? 1.0f : 0.0f;
    }
}

extern "C" void kernel_launch(void* const* d_in, const int* in_sizes, int n_in,
                              void* d_out, int out_size, void* d_ws, size_t ws_size,
                              hipStream_t stream) {
    const float* feat = (const float*)d_in[0];
    const int* h_ori  = (const int*)d_in[1];
    const int* w_ori  = (const int*)d_in[2];
    float* out = (float*)d_out;

    float4* ws_box  = (float4*)d_ws;
    float*  ws_score = (float*)((char*)d_ws + sizeof(float4) * BATCH * NCELL);

    int total = BATCH * NCELL;
    decode_kernel<<<(total + 255) / 256, 256, 0, stream>>>(
        feat, h_ori, w_ori, out, ws_box, ws_score);
    nms_kernel<<<BATCH, SORTN, 0, stream>>>(ws_box, ws_score, out);
}